// Round 11
// baseline (651.675 us; speedup 1.0000x reference)
//
#include <hip/hip_runtime.h>
#include <hip/hip_fp16.h>

#define WS_ALIGN(x) (((x) + size_t(255)) & ~size_t(255))
#define NB1  8
#define NSUB 128            // sub-buckets per bucket
#define NSB  (NB1 * NSUB)   // 1024 total
#define SPG  98             // cols per sub-bucket = ceil(12500/128)
#define CAP1 262144
#define CAP2 3072           // mean 1562 edges/sub, std ~40 -> huge margin

// ---- Phase A: partition edges into 8 col-range buckets. Packed edge:
// row (17b) << 14 | local_col (14b, < 12500). Block-tiled LDS histogram ->
// ONE padded global atomicAdd per bucket per block.
__global__ __launch_bounds__(256) void k_bucket(const int* __restrict__ row,
                                                const int* __restrict__ col,
                                                int* __restrict__ bcur,   // stride 16 ints
                                                unsigned int* __restrict__ pairs,
                                                int E, unsigned int magic, int npg) {
    __shared__ int lcnt[4][8];
    __shared__ int wbase[4][8];
    int wid = threadIdx.x >> 6;
    if (threadIdx.x < 32) lcnt[threadIdx.x >> 3][threadIdx.x & 7] = 0;
    __syncthreads();

    int t0 = blockIdx.x * 2048;
    int b[8], rk[8];
    unsigned int pk[8];
#pragma unroll
    for (int k = 0; k < 8; k++) {
        int e = t0 + k * 256 + threadIdx.x;
        b[k] = -1;
        if (e < E) {
            int r = row[e], c = col[e];
            int bb = (int)(((unsigned long long)(unsigned)c * magic) >> 44);  // c/npg
            b[k] = bb;
            pk[k] = ((unsigned)r << 14) | (unsigned)(c - bb * npg);
            rk[k] = atomicAdd(&lcnt[wid][bb], 1);
        }
    }
    __syncthreads();
    if (threadIdx.x < 8) {
        int bb = threadIdx.x;
        int c0 = lcnt[0][bb], c1 = lcnt[1][bb], c2 = lcnt[2][bb], c3 = lcnt[3][bb];
        int tot = (c0 + c1) + (c2 + c3);
        int base = tot ? atomicAdd(&bcur[bb * 16], tot) : 0;
        wbase[0][bb] = base;
        wbase[1][bb] = base + c0;
        wbase[2][bb] = base + c0 + c1;
        wbase[3][bb] = base + c0 + c1 + c2;
    }
    __syncthreads();
#pragma unroll
    for (int k = 0; k < 8; k++) {
        if (b[k] >= 0)
            pairs[(size_t)b[k] * CAP1 + wbase[wid][b[k]] + rk[k]] = pk[k];
    }
}

// ---- Phase B: refine bucket b into 128 sub-buckets of SPG cols (lc/98 via magic).
__global__ __launch_bounds__(256) void k_refine(const unsigned int* __restrict__ pairs1,
                                                const int* __restrict__ bcur,
                                                int* __restrict__ bcur2,  // stride 16 ints
                                                unsigned int* __restrict__ pairs2,
                                                unsigned int magic2) {
    __shared__ int lcnt[4][NSUB];
    __shared__ int wbase[4][NSUB];
    int b = blockIdx.x & 7;
    int j = blockIdx.x >> 3;
    int nblk = gridDim.x >> 3;
    int wid = threadIdx.x >> 6;
    int cnt = bcur[b * 16];
    const unsigned int* src = pairs1 + (size_t)b * CAP1;
    unsigned int* dst = pairs2 + (size_t)b * NSUB * CAP2;
    int* mycur = bcur2 + b * NSUB * 16;

    for (int t0 = j * 4096; t0 < cnt; t0 += nblk * 4096) {
        for (int q = threadIdx.x; q < NSUB; q += 256) {
            lcnt[0][q] = 0; lcnt[1][q] = 0; lcnt[2][q] = 0; lcnt[3][q] = 0;
        }
        __syncthreads();
        unsigned int pk[16];
        int sb[16], rk[16];
#pragma unroll
        for (int k = 0; k < 16; k++) {
            int e = t0 + k * 256 + threadIdx.x;
            sb[k] = -1;
            if (e < cnt) {
                pk[k] = src[e];
                sb[k] = (int)(((pk[k] & 16383u) * magic2) >> 20);   // lc/SPG
                rk[k] = atomicAdd(&lcnt[wid][sb[k]], 1);
            }
        }
        __syncthreads();
        for (int q = threadIdx.x; q < NSUB; q += 256) {
            int c0 = lcnt[0][q], c1 = lcnt[1][q], c2 = lcnt[2][q], c3 = lcnt[3][q];
            int tot = (c0 + c1) + (c2 + c3);
            int base = tot ? atomicAdd(&mycur[q * 16], tot) : 0;
            wbase[0][q] = base;
            wbase[1][q] = base + c0;
            wbase[2][q] = base + c0 + c1;
            wbase[3][q] = base + c0 + c1 + c2;
        }
        __syncthreads();
#pragma unroll
        for (int k = 0; k < 16; k++) {
            if (sb[k] >= 0)
                dst[(size_t)sb[k] * CAP2 + wbase[wid][sb[k]] + rk[k]] = pk[k];
        }
        __syncthreads();
    }
}

// ---- degree -> dinv directly (no deg array, no scan, no offs).
__global__ __launch_bounds__(256) void k_degdinv(const unsigned int* __restrict__ pairs2,
                                                 const int* __restrict__ bcur2,
                                                 float* __restrict__ dinv, int npg) {
    __shared__ int hist[SPG];
    int sbid = blockIdx.x;
    int b = sbid >> 7, s = sbid & (NSUB - 1);
    int cnt = bcur2[sbid * 16];
    int sbase = s * SPG;
    int ncols = min(SPG, npg - sbase);
    const unsigned int* src = pairs2 + (size_t)sbid * CAP2;
    for (int q = threadIdx.x; q < SPG; q += 256) hist[q] = 0;
    __syncthreads();
    for (int i = threadIdx.x; i < cnt; i += 256)
        atomicAdd(&hist[(int)(src[i] & 16383u) - sbase], 1);
    __syncthreads();
    if (threadIdx.x < ncols)
        dinv[b * npg + sbase + threadIdx.x] = rsqrtf((float)(hist[threadIdx.x] + 1));
}

// h1s = fp16[(x @ W1) * dinv[node]]   x:[n,128] W1:[128,64]
__global__ __launch_bounds__(256) void k_gemm1(const float* __restrict__ x,
                                               const float* __restrict__ W1,
                                               const float* __restrict__ dinv,
                                               __half* __restrict__ h1s, int n) {
    __shared__ float xs[32][132];
    __shared__ float Ws[128][64];
    int base = blockIdx.x * 32;
    for (int q = threadIdx.x; q < 1024; q += 256) {
        int nd = q >> 5, kf = q & 31;
        int gn = base + nd;
        float4 v = (gn < n) ? *(const float4*)&x[(size_t)gn * 128 + kf * 4]
                            : make_float4(0.f, 0.f, 0.f, 0.f);
        *(float4*)&xs[nd][kf * 4] = v;
    }
    for (int q = threadIdx.x; q < 2048; q += 256) {
        float4 v = ((const float4*)W1)[q];
        int k = q >> 4, cf = q & 15;
        *(float4*)&Ws[k][cf * 4] = v;
    }
    __syncthreads();

    int wid = threadIdx.x >> 6, lane = threadIdx.x & 63;
    int r = (wid << 3) + (lane & 7);
    int cbase = (lane >> 3) << 3;
    float4 a0 = make_float4(0.f, 0.f, 0.f, 0.f);
    float4 a1 = make_float4(0.f, 0.f, 0.f, 0.f);
#pragma unroll 4
    for (int k4 = 0; k4 < 32; k4++) {
        float4 xv = *(const float4*)&xs[r][k4 * 4];
#pragma unroll
        for (int kk = 0; kk < 4; kk++) {
            float xk = (&xv.x)[kk];
            float4 w0 = *(const float4*)&Ws[k4 * 4 + kk][cbase];
            float4 w1 = *(const float4*)&Ws[k4 * 4 + kk][cbase + 4];
            a0.x = fmaf(xk, w0.x, a0.x); a0.y = fmaf(xk, w0.y, a0.y);
            a0.z = fmaf(xk, w0.z, a0.z); a0.w = fmaf(xk, w0.w, a0.w);
            a1.x = fmaf(xk, w1.x, a1.x); a1.y = fmaf(xk, w1.y, a1.y);
            a1.z = fmaf(xk, w1.z, a1.z); a1.w = fmaf(xk, w1.w, a1.w);
        }
    }
    int node = base + r;
    if (node < n) {
        float di = dinv[node];
        __half2 h0 = __floats2half2_rn(a0.x * di, a0.y * di);
        __half2 h1 = __floats2half2_rn(a0.z * di, a0.w * di);
        __half2 h2 = __floats2half2_rn(a1.x * di, a1.y * di);
        __half2 h3 = __floats2half2_rn(a1.z * di, a1.w * di);
        __half2* o = (__half2*)&h1s[(size_t)node * 64 + cbase];
        o[0] = h0; o[1] = h1; o[2] = h2; o[3] = h3;
    }
}

// ---- Fused layer-1 aggregation + layer-2 GEMM, straight from sub-buckets.
// Block owns SPG dest cols; accum[SPG][64] fp32 in LDS. Per edge: wave-uniform
// scalar pk load -> 128B row gather (scalar base + lane offset) -> ds_add_f32.
// No CSR, no adj, no global atomics. 1024 blocks = exactly 4/CU.
__global__ __launch_bounds__(256) void k_agg1f(const __half* __restrict__ h1s,
                                               const float* __restrict__ dinv,
                                               const unsigned int* __restrict__ pairs2,
                                               const int* __restrict__ bcur2,
                                               const float* __restrict__ b1,
                                               const float* __restrict__ W2,
                                               float* __restrict__ h2s, int npg) {
    __shared__ float accum[SPG * 64];
    int sbid = blockIdx.x;
    int b = sbid >> 7, s = sbid & (NSUB - 1);
    int cnt = __builtin_amdgcn_readfirstlane(bcur2[sbid * 16]);
    int sbase = s * SPG;
    int colbase = b * npg + sbase;
    int ncols = min(SPG, npg - sbase);
    const unsigned int* src = pairs2 + (size_t)sbid * CAP2;

    float4* az = (float4*)accum;
    for (int q = threadIdx.x; q < SPG * 16; q += 256) az[q] = make_float4(0.f, 0.f, 0.f, 0.f);
    __syncthreads();

    int wid = __builtin_amdgcn_readfirstlane(threadIdx.x >> 6);
    int lane = threadIdx.x & 63;
    int per = (cnt + 3) >> 2;
    int ws = wid * per;
    int we = min(ws + per, cnt);
    int p = ws;
    for (; p + 8 <= we; p += 8) {
#pragma unroll
        for (int k = 0; k < 8; k++) {
            unsigned int pk = src[p + k];                 // wave-uniform scalar load
            int sn = (int)(pk >> 14);
            int lc = (int)(pk & 16383u) - sbase;
            float v = __half2float(h1s[(size_t)sn * 64 + lane]);
            atomicAdd(&accum[lc * 64 + lane], v);         // ds_add_f32
        }
    }
    for (; p < we; p++) {
        unsigned int pk = src[p];
        int sn = (int)(pk >> 14);
        int lc = (int)(pk & 16383u) - sbase;
        atomicAdd(&accum[lc * 64 + lane], __half2float(h1s[(size_t)sn * 64 + lane]));
    }
    __syncthreads();

    // epilogue: relu(di*(accum+self)+b1) then W2 reduce across 64 lanes
    float w0 = W2[lane * 2], w1 = W2[lane * 2 + 1];
    float bv = b1[lane];
    for (int nd = wid; nd < ncols; nd += 4) {
        int i = colbase + nd;
        float di = dinv[i];
        float self = __half2float(h1s[(size_t)i * 64 + lane]);
        float val = fmaxf(fmaf(di, accum[nd * 64 + lane] + self, bv), 0.f);
        float t0 = val * w0, t1 = val * w1;
#pragma unroll
        for (int m = 1; m < 64; m <<= 1) {
            t0 += __shfl_xor(t0, m, 64);
            t1 += __shfl_xor(t1, m, 64);
        }
        if (lane == 0) {
            h2s[(size_t)i * 2]     = t0 * di;
            h2s[(size_t)i * 2 + 1] = t1 * di;
        }
    }
}

// ---- Fused layer-2 aggregation from sub-buckets. Lane-per-edge, 8B gathers
// from L2-resident h2s, 2 LDS float atomics per edge.
__global__ __launch_bounds__(256) void k_agg2f(const float* __restrict__ h2s,
                                               const float* __restrict__ dinv,
                                               const unsigned int* __restrict__ pairs2,
                                               const int* __restrict__ bcur2,
                                               const float* __restrict__ b2,
                                               float* __restrict__ out, int npg) {
    __shared__ float acc2[SPG * 2];
    int sbid = blockIdx.x;
    int b = sbid >> 7, s = sbid & (NSUB - 1);
    int cnt = bcur2[sbid * 16];
    int sbase = s * SPG;
    int colbase = b * npg + sbase;
    int ncols = min(SPG, npg - sbase);
    const unsigned int* src = pairs2 + (size_t)sbid * CAP2;
    for (int q = threadIdx.x; q < SPG * 2; q += 256) acc2[q] = 0.f;
    __syncthreads();
    for (int i = threadIdx.x; i < cnt; i += 256) {
        unsigned int pk = src[i];
        int sn = (int)(pk >> 14);
        int lc = (int)(pk & 16383u) - sbase;
        float2 v = *(const float2*)(h2s + (size_t)sn * 2);
        atomicAdd(&acc2[lc * 2], v.x);
        atomicAdd(&acc2[lc * 2 + 1], v.y);
    }
    __syncthreads();
    if (threadIdx.x < ncols) {
        int i = colbase + threadIdx.x;
        float di = dinv[i];
        float2 hv = *(const float2*)(h2s + (size_t)i * 2);
        out[(size_t)i * 2]     = fmaf(di, acc2[threadIdx.x * 2] + hv.x, b2[0]);
        out[(size_t)i * 2 + 1] = fmaf(di, acc2[threadIdx.x * 2 + 1] + hv.y, b2[1]);
    }
}

extern "C" void kernel_launch(void* const* d_in, const int* in_sizes, int n_in,
                              void* d_out, int out_size, void* d_ws, size_t ws_size,
                              hipStream_t stream) {
    const float* x  = (const float*)d_in[0];
    const int*   ei = (const int*)d_in[1];
    const float* W1 = (const float*)d_in[2];
    const float* b1 = (const float*)d_in[3];
    const float* W2 = (const float*)d_in[4];
    const float* b2 = (const float*)d_in[5];
    float* out = (float*)d_out;

    int N = in_sizes[0] / 128;   // 100000
    int E = in_sizes[1] / 2;     // 1600000
    const int* row = ei;
    const int* col = ei + E;

    char* ws = (char*)d_ws;
    size_t off = 0;
    auto alloc = [&](size_t bytes) -> char* {
        char* p = ws + off;
        off = WS_ALIGN(off + bytes);
        return p;
    };
    int*   bcur   = (int*)alloc(512 + (size_t)NSB * 64);   // bcur (8x16) + bcur2 (1024x16)
    int*   bcur2  = bcur + 128;
    float* dinv   = (float*)alloc((size_t)N * 4);
    unsigned int* pairs1 = (unsigned int*)alloc((size_t)NB1 * CAP1 * 4);   // 8.4MB
    unsigned int* pairs2 = (unsigned int*)alloc((size_t)NSB * CAP2 * 4);   // 12.6MB (lives through agg)
    __half* h1s   = (__half*)alloc((size_t)N * 64 * 2);    // 12.8MB fp16
    float* h2s    = (float*)alloc((size_t)N * 2 * 4);

    int npg = (N + 7) / 8;                                  // 12500
    unsigned int magic = (unsigned int)(((1ULL << 44) + (unsigned long long)npg - 1)
                                        / (unsigned long long)npg);
    unsigned int magic2 = (unsigned int)(((1u << 20) + SPG - 1) / SPG);  // /98, exact for lc<12500

    hipMemsetAsync(bcur, 0, 512 + (size_t)NSB * 64, stream);
    hipLaunchKernelGGL(k_bucket, dim3((E + 2047) / 2048), dim3(256), 0, stream,
                       row, col, bcur, pairs1, E, magic, npg);
    hipLaunchKernelGGL(k_refine, dim3(512), dim3(256), 0, stream,
                       pairs1, bcur, bcur2, pairs2, magic2);
    hipLaunchKernelGGL(k_degdinv, dim3(NSB), dim3(256), 0, stream, pairs2, bcur2, dinv, npg);
    hipLaunchKernelGGL(k_gemm1, dim3((N + 31) / 32), dim3(256), 0, stream, x, W1, dinv, h1s, N);
    hipLaunchKernelGGL(k_agg1f, dim3(NSB), dim3(256), 0, stream,
                       h1s, dinv, pairs2, bcur2, b1, W2, h2s, npg);
    hipLaunchKernelGGL(k_agg2f, dim3(NSB), dim3(256), 0, stream,
                       h2s, dinv, pairs2, bcur2, b2, out, npg);
}

// Round 12
// 176.677 us; speedup vs baseline: 3.6885x; 3.6885x over previous
//
#include <hip/hip_runtime.h>
#include <hip/hip_fp16.h>

#define WS_ALIGN(x) (((x) + size_t(255)) & ~size_t(255))
#define NB1  8
#define NSUB 128            // sub-buckets per bucket
#define NSB  (NB1 * NSUB)   // 1024 total
#define SPG  98             // cols per sub-bucket = ceil(12500/128)
#define CAP1 262144
#define CAP2 3072           // mean 1562 edges/sub, sigma ~40 -> huge margin

// ---- Phase A: partition edges into 8 col-range buckets. Packed edge:
// row (17b) << 14 | local_col (14b, < 12500). Block-tiled LDS histogram ->
// ONE padded global atomicAdd per bucket per block.
__global__ __launch_bounds__(256) void k_bucket(const int* __restrict__ row,
                                                const int* __restrict__ col,
                                                int* __restrict__ bcur,   // stride 16 ints
                                                unsigned int* __restrict__ pairs,
                                                int E, unsigned int magic, int npg) {
    __shared__ int lcnt[4][8];
    __shared__ int wbase[4][8];
    int wid = threadIdx.x >> 6;
    if (threadIdx.x < 32) lcnt[threadIdx.x >> 3][threadIdx.x & 7] = 0;
    __syncthreads();

    int t0 = blockIdx.x * 2048;
    int b[8], rk[8];
    unsigned int pk[8];
#pragma unroll
    for (int k = 0; k < 8; k++) {
        int e = t0 + k * 256 + threadIdx.x;
        b[k] = -1;
        if (e < E) {
            int r = row[e], c = col[e];
            int bb = (int)(((unsigned long long)(unsigned)c * magic) >> 44);  // c/npg
            b[k] = bb;
            pk[k] = ((unsigned)r << 14) | (unsigned)(c - bb * npg);
            rk[k] = atomicAdd(&lcnt[wid][bb], 1);
        }
    }
    __syncthreads();
    if (threadIdx.x < 8) {
        int bb = threadIdx.x;
        int c0 = lcnt[0][bb], c1 = lcnt[1][bb], c2 = lcnt[2][bb], c3 = lcnt[3][bb];
        int tot = (c0 + c1) + (c2 + c3);
        int base = tot ? atomicAdd(&bcur[bb * 16], tot) : 0;
        wbase[0][bb] = base;
        wbase[1][bb] = base + c0;
        wbase[2][bb] = base + c0 + c1;
        wbase[3][bb] = base + c0 + c1 + c2;
    }
    __syncthreads();
#pragma unroll
    for (int k = 0; k < 8; k++) {
        if (b[k] >= 0)
            pairs[(size_t)b[k] * CAP1 + wbase[wid][b[k]] + rk[k]] = pk[k];
    }
}

// ---- Phase B: refine bucket b into 128 sub-buckets of SPG cols (lc/98 via magic).
__global__ __launch_bounds__(256) void k_refine(const unsigned int* __restrict__ pairs1,
                                                const int* __restrict__ bcur,
                                                int* __restrict__ bcur2,  // stride 16 ints
                                                unsigned int* __restrict__ pairs2,
                                                unsigned int magic2) {
    __shared__ int lcnt[4][NSUB];
    __shared__ int wbase[4][NSUB];
    int b = blockIdx.x & 7;
    int j = blockIdx.x >> 3;
    int nblk = gridDim.x >> 3;
    int wid = threadIdx.x >> 6;
    int cnt = bcur[b * 16];
    const unsigned int* src = pairs1 + (size_t)b * CAP1;
    unsigned int* dst = pairs2 + (size_t)b * NSUB * CAP2;
    int* mycur = bcur2 + b * NSUB * 16;

    for (int t0 = j * 4096; t0 < cnt; t0 += nblk * 4096) {
        for (int q = threadIdx.x; q < NSUB; q += 256) {
            lcnt[0][q] = 0; lcnt[1][q] = 0; lcnt[2][q] = 0; lcnt[3][q] = 0;
        }
        __syncthreads();
        unsigned int pk[16];
        int sb[16], rk[16];
#pragma unroll
        for (int k = 0; k < 16; k++) {
            int e = t0 + k * 256 + threadIdx.x;
            sb[k] = -1;
            if (e < cnt) {
                pk[k] = src[e];
                sb[k] = (int)(((pk[k] & 16383u) * magic2) >> 20);   // lc/SPG
                rk[k] = atomicAdd(&lcnt[wid][sb[k]], 1);
            }
        }
        __syncthreads();
        for (int q = threadIdx.x; q < NSUB; q += 256) {
            int c0 = lcnt[0][q], c1 = lcnt[1][q], c2 = lcnt[2][q], c3 = lcnt[3][q];
            int tot = (c0 + c1) + (c2 + c3);
            int base = tot ? atomicAdd(&mycur[q * 16], tot) : 0;
            wbase[0][q] = base;
            wbase[1][q] = base + c0;
            wbase[2][q] = base + c0 + c1;
            wbase[3][q] = base + c0 + c1 + c2;
        }
        __syncthreads();
#pragma unroll
        for (int k = 0; k < 16; k++) {
            if (sb[k] >= 0)
                dst[(size_t)sb[k] * CAP2 + wbase[wid][sb[k]] + rk[k]] = pk[k];
        }
        __syncthreads();
    }
}

// ---- degree -> dinv directly (needed by gemm1 for pre-scaling).
__global__ __launch_bounds__(256) void k_degdinv(const unsigned int* __restrict__ pairs2,
                                                 const int* __restrict__ bcur2,
                                                 float* __restrict__ dinv, int npg) {
    __shared__ int hist[SPG];
    int sbid = blockIdx.x;
    int b = sbid >> 7, s = sbid & (NSUB - 1);
    int cnt = bcur2[sbid * 16];
    int sbase = s * SPG;
    int ncols = min(SPG, npg - sbase);
    const unsigned int* src = pairs2 + (size_t)sbid * CAP2;
    for (int q = threadIdx.x; q < SPG; q += 256) hist[q] = 0;
    __syncthreads();
    for (int i = threadIdx.x; i < cnt; i += 256)
        atomicAdd(&hist[(int)(src[i] & 16383u) - sbase], 1);
    __syncthreads();
    if (threadIdx.x < ncols)
        dinv[b * npg + sbase + threadIdx.x] = rsqrtf((float)(hist[threadIdx.x] + 1));
}

// h1s = fp16[(x @ W1) * dinv[node]]   x:[n,128] W1:[128,64]
__global__ __launch_bounds__(256) void k_gemm1(const float* __restrict__ x,
                                               const float* __restrict__ W1,
                                               const float* __restrict__ dinv,
                                               __half* __restrict__ h1s, int n) {
    __shared__ float xs[32][132];
    __shared__ float Ws[128][64];
    int base = blockIdx.x * 32;
    for (int q = threadIdx.x; q < 1024; q += 256) {
        int nd = q >> 5, kf = q & 31;
        int gn = base + nd;
        float4 v = (gn < n) ? *(const float4*)&x[(size_t)gn * 128 + kf * 4]
                            : make_float4(0.f, 0.f, 0.f, 0.f);
        *(float4*)&xs[nd][kf * 4] = v;
    }
    for (int q = threadIdx.x; q < 2048; q += 256) {
        float4 v = ((const float4*)W1)[q];
        int k = q >> 4, cf = q & 15;
        *(float4*)&Ws[k][cf * 4] = v;
    }
    __syncthreads();

    int wid = threadIdx.x >> 6, lane = threadIdx.x & 63;
    int r = (wid << 3) + (lane & 7);
    int cbase = (lane >> 3) << 3;
    float4 a0 = make_float4(0.f, 0.f, 0.f, 0.f);
    float4 a1 = make_float4(0.f, 0.f, 0.f, 0.f);
#pragma unroll 4
    for (int k4 = 0; k4 < 32; k4++) {
        float4 xv = *(const float4*)&xs[r][k4 * 4];
#pragma unroll
        for (int kk = 0; kk < 4; kk++) {
            float xk = (&xv.x)[kk];
            float4 w0 = *(const float4*)&Ws[k4 * 4 + kk][cbase];
            float4 w1 = *(const float4*)&Ws[k4 * 4 + kk][cbase + 4];
            a0.x = fmaf(xk, w0.x, a0.x); a0.y = fmaf(xk, w0.y, a0.y);
            a0.z = fmaf(xk, w0.z, a0.z); a0.w = fmaf(xk, w0.w, a0.w);
            a1.x = fmaf(xk, w1.x, a1.x); a1.y = fmaf(xk, w1.y, a1.y);
            a1.z = fmaf(xk, w1.z, a1.z); a1.w = fmaf(xk, w1.w, a1.w);
        }
    }
    int node = base + r;
    if (node < n) {
        float di = dinv[node];
        __half2 h0 = __floats2half2_rn(a0.x * di, a0.y * di);
        __half2 h1 = __floats2half2_rn(a0.z * di, a0.w * di);
        __half2 h2 = __floats2half2_rn(a1.x * di, a1.y * di);
        __half2 h3 = __floats2half2_rn(a1.z * di, a1.w * di);
        __half2* o = (__half2*)&h1s[(size_t)node * 64 + cbase];
        o[0] = h0; o[1] = h1; o[2] = h2; o[3] = h3;
    }
}

// ---- Fused: LDS counting-sort of the sub-bucket's edges, then the proven
// round-8 register-accumulating CSR gather (wave per node, lane = channel,
// 4 independent half gathers in flight; NO DS ops in the gather chain),
// then relu + fused W2 shuffle-reduce. Replaces degcnt/scan/offs/binsort.
__global__ __launch_bounds__(256) void k_agg1s(const __half* __restrict__ h1s,
                                               const float* __restrict__ dinv,
                                               const unsigned int* __restrict__ pairs2,
                                               const int* __restrict__ bcur2,
                                               const float* __restrict__ b1,
                                               const float* __restrict__ W2,
                                               float* __restrict__ h2s, int npg) {
    __shared__ int hist[SPG + 2];
    __shared__ int offsL[SPG + 2];
    __shared__ int curL[SPG + 2];
    __shared__ int adjL[CAP2];          // 12 KB
    int sbid = blockIdx.x;
    int b = sbid >> 7, s = sbid & (NSUB - 1);
    int cnt = bcur2[sbid * 16];
    int sbase = s * SPG;
    int colbase = b * npg + sbase;
    int ncols = min(SPG, npg - sbase);
    const unsigned int* src = pairs2 + (size_t)sbid * CAP2;

    for (int q = threadIdx.x; q < SPG + 2; q += 256) hist[q] = 0;
    __syncthreads();
    for (int i = threadIdx.x; i < cnt; i += 256)
        atomicAdd(&hist[(int)(src[i] & 16383u) - sbase], 1);
    __syncthreads();
    // wave 0: exclusive scan of hist[0..SPG) -> offsL
    if (threadIdx.x < 64) {
        int lane = threadIdx.x;
        int v0 = hist[lane];
        int sc0 = v0;
#pragma unroll
        for (int m = 1; m < 64; m <<= 1) {
            int t = __shfl_up(sc0, m, 64);
            if (lane >= m) sc0 += t;
        }
        offsL[lane] = sc0 - v0;
        int tot0 = __shfl(sc0, 63, 64);
        int v1 = (lane < SPG - 64) ? hist[64 + lane] : 0;
        int sc1 = v1;
#pragma unroll
        for (int m = 1; m < 64; m <<= 1) {
            int t = __shfl_up(sc1, m, 64);
            if (lane >= m) sc1 += t;
        }
        if (lane < SPG - 64 + 1) offsL[64 + lane] = tot0 + sc1 - v1;  // includes offsL[SPG]
        if (lane == 0) offsL[SPG] = cnt;
    }
    __syncthreads();
    for (int q = threadIdx.x; q < SPG + 1; q += 256) curL[q] = offsL[q];
    __syncthreads();
    // scatter rows into LDS (throughput ops, not on a latency chain)
    for (int i = threadIdx.x; i < cnt; i += 256) {
        unsigned int pk = src[i];
        int lc = (int)(pk & 16383u) - sbase;
        int pos = atomicAdd(&curL[lc], 1);
        adjL[pos] = (int)(pk >> 14);
    }
    __syncthreads();

    // gather phase: wave per node, stride 4
    int wid = threadIdx.x >> 6, lane = threadIdx.x & 63;
    float w0 = W2[lane * 2], w1 = W2[lane * 2 + 1], bv = b1[lane];
    for (int nd = wid; nd < ncols; nd += 4) {
        int st = offsL[nd], en = offsL[nd + 1];
        float acc0 = 0.f, acc1 = 0.f, acc2 = 0.f, acc3 = 0.f;
        int p = st;
        for (; p + 4 <= en; p += 4) {
            int s0 = adjL[p], s1 = adjL[p + 1], s2 = adjL[p + 2], s3 = adjL[p + 3];
            acc0 += __half2float(h1s[(size_t)s0 * 64 + lane]);
            acc1 += __half2float(h1s[(size_t)s1 * 64 + lane]);
            acc2 += __half2float(h1s[(size_t)s2 * 64 + lane]);
            acc3 += __half2float(h1s[(size_t)s3 * 64 + lane]);
        }
        int rem = en - p;
        if (rem > 0) {
            int q0 = adjL[p];
            int q1 = (rem > 1) ? adjL[p + 1] : q0;
            int q2 = (rem > 2) ? adjL[p + 2] : q0;
            float v0 = __half2float(h1s[(size_t)q0 * 64 + lane]);
            float v1 = __half2float(h1s[(size_t)q1 * 64 + lane]);
            float v2 = __half2float(h1s[(size_t)q2 * 64 + lane]);
            acc0 += v0;
            if (rem > 1) acc1 += v1;
            if (rem > 2) acc2 += v2;
        }
        float acc = (acc0 + acc1) + (acc2 + acc3);
        int i = colbase + nd;
        float di = dinv[i];
        float self = __half2float(h1s[(size_t)i * 64 + lane]);
        float val = fmaxf(fmaf(di, acc + self, bv), 0.f);
        float t0 = val * w0, t1 = val * w1;
#pragma unroll
        for (int m = 1; m < 64; m <<= 1) {
            t0 += __shfl_xor(t0, m, 64);
            t1 += __shfl_xor(t1, m, 64);
        }
        if (lane == 0) {
            h2s[(size_t)i * 2]     = t0 * di;
            h2s[(size_t)i * 2 + 1] = t1 * di;
        }
    }
}

// ---- Layer-2 aggregation from sub-buckets (r11, measured cheap). Lane-per-
// edge, 8B gathers from L2-resident h2s, 2 LDS float atomics per edge.
__global__ __launch_bounds__(256) void k_agg2f(const float* __restrict__ h2s,
                                               const float* __restrict__ dinv,
                                               const unsigned int* __restrict__ pairs2,
                                               const int* __restrict__ bcur2,
                                               const float* __restrict__ b2,
                                               float* __restrict__ out, int npg) {
    __shared__ float acc2[SPG * 2];
    int sbid = blockIdx.x;
    int b = sbid >> 7, s = sbid & (NSUB - 1);
    int cnt = bcur2[sbid * 16];
    int sbase = s * SPG;
    int colbase = b * npg + sbase;
    int ncols = min(SPG, npg - sbase);
    const unsigned int* src = pairs2 + (size_t)sbid * CAP2;
    for (int q = threadIdx.x; q < SPG * 2; q += 256) acc2[q] = 0.f;
    __syncthreads();
    for (int i = threadIdx.x; i < cnt; i += 256) {
        unsigned int pk = src[i];
        int sn = (int)(pk >> 14);
        int lc = (int)(pk & 16383u) - sbase;
        float2 v = *(const float2*)(h2s + (size_t)sn * 2);
        atomicAdd(&acc2[lc * 2], v.x);
        atomicAdd(&acc2[lc * 2 + 1], v.y);
    }
    __syncthreads();
    if (threadIdx.x < ncols) {
        int i = colbase + threadIdx.x;
        float di = dinv[i];
        float2 hv = *(const float2*)(h2s + (size_t)i * 2);
        out[(size_t)i * 2]     = fmaf(di, acc2[threadIdx.x * 2] + hv.x, b2[0]);
        out[(size_t)i * 2 + 1] = fmaf(di, acc2[threadIdx.x * 2 + 1] + hv.y, b2[1]);
    }
}

extern "C" void kernel_launch(void* const* d_in, const int* in_sizes, int n_in,
                              void* d_out, int out_size, void* d_ws, size_t ws_size,
                              hipStream_t stream) {
    const float* x  = (const float*)d_in[0];
    const int*   ei = (const int*)d_in[1];
    const float* W1 = (const float*)d_in[2];
    const float* b1 = (const float*)d_in[3];
    const float* W2 = (const float*)d_in[4];
    const float* b2 = (const float*)d_in[5];
    float* out = (float*)d_out;

    int N = in_sizes[0] / 128;   // 100000
    int E = in_sizes[1] / 2;     // 1600000
    const int* row = ei;
    const int* col = ei + E;

    char* ws = (char*)d_ws;
    size_t off = 0;
    auto alloc = [&](size_t bytes) -> char* {
        char* p = ws + off;
        off = WS_ALIGN(off + bytes);
        return p;
    };
    int*   bcur   = (int*)alloc(512 + (size_t)NSB * 64);   // bcur (8x16) + bcur2 (1024x16)
    int*   bcur2  = bcur + 128;
    float* dinv   = (float*)alloc((size_t)N * 4);
    unsigned int* pairs1 = (unsigned int*)alloc((size_t)NB1 * CAP1 * 4);   // 8.4MB
    unsigned int* pairs2 = (unsigned int*)alloc((size_t)NSB * CAP2 * 4);   // 12.6MB
    __half* h1s   = (__half*)alloc((size_t)N * 64 * 2);    // 12.8MB fp16
    float* h2s    = (float*)alloc((size_t)N * 2 * 4);

    int npg = (N + 7) / 8;                                  // 12500
    unsigned int magic = (unsigned int)(((1ULL << 44) + (unsigned long long)npg - 1)
                                        / (unsigned long long)npg);
    unsigned int magic2 = (unsigned int)(((1u << 20) + SPG - 1) / SPG);  // /98, exact for lc<12544

    hipMemsetAsync(bcur, 0, 512 + (size_t)NSB * 64, stream);
    hipLaunchKernelGGL(k_bucket, dim3((E + 2047) / 2048), dim3(256), 0, stream,
                       row, col, bcur, pairs1, E, magic, npg);
    hipLaunchKernelGGL(k_refine, dim3(512), dim3(256), 0, stream,
                       pairs1, bcur, bcur2, pairs2, magic2);
    hipLaunchKernelGGL(k_degdinv, dim3(NSB), dim3(256), 0, stream, pairs2, bcur2, dinv, npg);
    hipLaunchKernelGGL(k_gemm1, dim3((N + 31) / 32), dim3(256), 0, stream, x, W1, dinv, h1s, N);
    hipLaunchKernelGGL(k_agg1s, dim3(NSB), dim3(256), 0, stream,
                       h1s, dinv, pairs2, bcur2, b1, W2, h2s, npg);
    hipLaunchKernelGGL(k_agg2f, dim3(NSB), dim3(256), 0, stream,
                       h2s, dinv, pairs2, bcur2, b2, out, npg);
}

// Round 13
// 150.088 us; speedup vs baseline: 4.3420x; 1.1772x over previous
//
#include <hip/hip_runtime.h>
#include <hip/hip_fp16.h>

#define WS_ALIGN(x) (((x) + size_t(255)) & ~size_t(255))
#define NB1  8
#define NSUB 128            // sub-buckets per bucket
#define NSB  (NB1 * NSUB)   // 1024 total
#define SPG  98             // cols per sub-bucket = ceil(12500/128)
#define CAP1 262144
#define CAP2 3072           // mean 1562 edges/sub, sigma ~40 -> huge margin

// ---- Phase A: partition edges into 8 col-range buckets. Packed edge:
// row (17b) << 14 | local_col (14b, < 12500). Block-tiled LDS histogram ->
// ONE padded global atomicAdd per bucket per block.
__global__ __launch_bounds__(256) void k_bucket(const int* __restrict__ row,
                                                const int* __restrict__ col,
                                                int* __restrict__ bcur,   // stride 16 ints
                                                unsigned int* __restrict__ pairs,
                                                int E, unsigned int magic, int npg) {
    __shared__ int lcnt[4][8];
    __shared__ int wbase[4][8];
    int wid = threadIdx.x >> 6;
    if (threadIdx.x < 32) lcnt[threadIdx.x >> 3][threadIdx.x & 7] = 0;
    __syncthreads();

    int t0 = blockIdx.x * 2048;
    int b[8], rk[8];
    unsigned int pk[8];
#pragma unroll
    for (int k = 0; k < 8; k++) {
        int e = t0 + k * 256 + threadIdx.x;
        b[k] = -1;
        if (e < E) {
            int r = row[e], c = col[e];
            int bb = (int)(((unsigned long long)(unsigned)c * magic) >> 44);  // c/npg
            b[k] = bb;
            pk[k] = ((unsigned)r << 14) | (unsigned)(c - bb * npg);
            rk[k] = atomicAdd(&lcnt[wid][bb], 1);
        }
    }
    __syncthreads();
    if (threadIdx.x < 8) {
        int bb = threadIdx.x;
        int c0 = lcnt[0][bb], c1 = lcnt[1][bb], c2 = lcnt[2][bb], c3 = lcnt[3][bb];
        int tot = (c0 + c1) + (c2 + c3);
        int base = tot ? atomicAdd(&bcur[bb * 16], tot) : 0;
        wbase[0][bb] = base;
        wbase[1][bb] = base + c0;
        wbase[2][bb] = base + c0 + c1;
        wbase[3][bb] = base + c0 + c1 + c2;
    }
    __syncthreads();
#pragma unroll
    for (int k = 0; k < 8; k++) {
        if (b[k] >= 0)
            pairs[(size_t)b[k] * CAP1 + wbase[wid][b[k]] + rk[k]] = pk[k];
    }
}

// ---- Phase B: refine bucket b into 128 sub-buckets of SPG cols (lc/98 via magic).
__global__ __launch_bounds__(256) void k_refine(const unsigned int* __restrict__ pairs1,
                                                const int* __restrict__ bcur,
                                                int* __restrict__ bcur2,  // stride 16 ints
                                                unsigned int* __restrict__ pairs2,
                                                unsigned int magic2) {
    __shared__ int lcnt[4][NSUB];
    __shared__ int wbase[4][NSUB];
    int b = blockIdx.x & 7;
    int j = blockIdx.x >> 3;
    int nblk = gridDim.x >> 3;
    int wid = threadIdx.x >> 6;
    int cnt = bcur[b * 16];
    const unsigned int* src = pairs1 + (size_t)b * CAP1;
    unsigned int* dst = pairs2 + (size_t)b * NSUB * CAP2;
    int* mycur = bcur2 + b * NSUB * 16;

    for (int t0 = j * 4096; t0 < cnt; t0 += nblk * 4096) {
        for (int q = threadIdx.x; q < NSUB; q += 256) {
            lcnt[0][q] = 0; lcnt[1][q] = 0; lcnt[2][q] = 0; lcnt[3][q] = 0;
        }
        __syncthreads();
        unsigned int pk[16];
        int sb[16], rk[16];
#pragma unroll
        for (int k = 0; k < 16; k++) {
            int e = t0 + k * 256 + threadIdx.x;
            sb[k] = -1;
            if (e < cnt) {
                pk[k] = src[e];
                sb[k] = (int)(((pk[k] & 16383u) * magic2) >> 20);   // lc/SPG
                rk[k] = atomicAdd(&lcnt[wid][sb[k]], 1);
            }
        }
        __syncthreads();
        for (int q = threadIdx.x; q < NSUB; q += 256) {
            int c0 = lcnt[0][q], c1 = lcnt[1][q], c2 = lcnt[2][q], c3 = lcnt[3][q];
            int tot = (c0 + c1) + (c2 + c3);
            int base = tot ? atomicAdd(&mycur[q * 16], tot) : 0;
            wbase[0][q] = base;
            wbase[1][q] = base + c0;
            wbase[2][q] = base + c0 + c1;
            wbase[3][q] = base + c0 + c1 + c2;
        }
        __syncthreads();
#pragma unroll
        for (int k = 0; k < 16; k++) {
            if (sb[k] >= 0)
                dst[(size_t)sb[k] * CAP2 + wbase[wid][sb[k]] + rk[k]] = pk[k];
        }
        __syncthreads();
    }
}

// ---- degree -> dinv directly (needed by gemm1 for pre-scaling).
__global__ __launch_bounds__(256) void k_degdinv(const unsigned int* __restrict__ pairs2,
                                                 const int* __restrict__ bcur2,
                                                 float* __restrict__ dinv, int npg) {
    __shared__ int hist[SPG];
    int sbid = blockIdx.x;
    int b = sbid >> 7, s = sbid & (NSUB - 1);
    int cnt = bcur2[sbid * 16];
    int sbase = s * SPG;
    int ncols = min(SPG, npg - sbase);
    const unsigned int* src = pairs2 + (size_t)sbid * CAP2;
    for (int q = threadIdx.x; q < SPG; q += 256) hist[q] = 0;
    __syncthreads();
    for (int i = threadIdx.x; i < cnt; i += 256)
        atomicAdd(&hist[(int)(src[i] & 16383u) - sbase], 1);
    __syncthreads();
    if (threadIdx.x < ncols)
        dinv[b * npg + sbase + threadIdx.x] = rsqrtf((float)(hist[threadIdx.x] + 1));
}

// h1s = fp16[(x @ W1) * dinv[node]]   x:[n,128] W1:[128,64]
__global__ __launch_bounds__(256) void k_gemm1(const float* __restrict__ x,
                                               const float* __restrict__ W1,
                                               const float* __restrict__ dinv,
                                               __half* __restrict__ h1s, int n) {
    __shared__ float xs[32][132];
    __shared__ float Ws[128][64];
    int base = blockIdx.x * 32;
    for (int q = threadIdx.x; q < 1024; q += 256) {
        int nd = q >> 5, kf = q & 31;
        int gn = base + nd;
        float4 v = (gn < n) ? *(const float4*)&x[(size_t)gn * 128 + kf * 4]
                            : make_float4(0.f, 0.f, 0.f, 0.f);
        *(float4*)&xs[nd][kf * 4] = v;
    }
    for (int q = threadIdx.x; q < 2048; q += 256) {
        float4 v = ((const float4*)W1)[q];
        int k = q >> 4, cf = q & 15;
        *(float4*)&Ws[k][cf * 4] = v;
    }
    __syncthreads();

    int wid = threadIdx.x >> 6, lane = threadIdx.x & 63;
    int r = (wid << 3) + (lane & 7);
    int cbase = (lane >> 3) << 3;
    float4 a0 = make_float4(0.f, 0.f, 0.f, 0.f);
    float4 a1 = make_float4(0.f, 0.f, 0.f, 0.f);
#pragma unroll 4
    for (int k4 = 0; k4 < 32; k4++) {
        float4 xv = *(const float4*)&xs[r][k4 * 4];
#pragma unroll
        for (int kk = 0; kk < 4; kk++) {
            float xk = (&xv.x)[kk];
            float4 w0 = *(const float4*)&Ws[k4 * 4 + kk][cbase];
            float4 w1 = *(const float4*)&Ws[k4 * 4 + kk][cbase + 4];
            a0.x = fmaf(xk, w0.x, a0.x); a0.y = fmaf(xk, w0.y, a0.y);
            a0.z = fmaf(xk, w0.z, a0.z); a0.w = fmaf(xk, w0.w, a0.w);
            a1.x = fmaf(xk, w1.x, a1.x); a1.y = fmaf(xk, w1.y, a1.y);
            a1.z = fmaf(xk, w1.z, a1.z); a1.w = fmaf(xk, w1.w, a1.w);
        }
    }
    int node = base + r;
    if (node < n) {
        float di = dinv[node];
        __half2 h0 = __floats2half2_rn(a0.x * di, a0.y * di);
        __half2 h1 = __floats2half2_rn(a0.z * di, a0.w * di);
        __half2 h2 = __floats2half2_rn(a1.x * di, a1.y * di);
        __half2 h3 = __floats2half2_rn(a1.z * di, a1.w * di);
        __half2* o = (__half2*)&h1s[(size_t)node * 64 + cbase];
        o[0] = h0; o[1] = h1; o[2] = h2; o[3] = h3;
    }
}

// ---- Fused: LDS counting-sort, then register-accumulating gather (wave per
// node, lane = channel, 4 independent half gathers in flight, adj from LDS),
// then relu + fused W2 shuffle-reduce.
// 512 threads (8 waves): 1024 blocks = 4 blocks/CU x 8 waves = 32 waves/CU.
__global__ __launch_bounds__(512) void k_agg1s(const __half* __restrict__ h1s,
                                               const float* __restrict__ dinv,
                                               const unsigned int* __restrict__ pairs2,
                                               const int* __restrict__ bcur2,
                                               const float* __restrict__ b1,
                                               const float* __restrict__ W2,
                                               float* __restrict__ h2s, int npg) {
    __shared__ int hist[SPG + 2];
    __shared__ int offsL[SPG + 2];
    __shared__ int curL[SPG + 2];
    __shared__ int adjL[CAP2];          // 12 KB
    int sbid = blockIdx.x;
    int b = sbid >> 7, s = sbid & (NSUB - 1);
    int cnt = bcur2[sbid * 16];
    int sbase = s * SPG;
    int colbase = b * npg + sbase;
    int ncols = min(SPG, npg - sbase);
    const unsigned int* src = pairs2 + (size_t)sbid * CAP2;

    for (int q = threadIdx.x; q < SPG + 2; q += 512) hist[q] = 0;
    __syncthreads();
    for (int i = threadIdx.x; i < cnt; i += 512)
        atomicAdd(&hist[(int)(src[i] & 16383u) - sbase], 1);
    __syncthreads();
    // wave 0: exclusive scan of hist[0..SPG) -> offsL
    if (threadIdx.x < 64) {
        int lane = threadIdx.x;
        int v0 = hist[lane];
        int sc0 = v0;
#pragma unroll
        for (int m = 1; m < 64; m <<= 1) {
            int t = __shfl_up(sc0, m, 64);
            if (lane >= m) sc0 += t;
        }
        offsL[lane] = sc0 - v0;
        int tot0 = __shfl(sc0, 63, 64);
        int v1 = (lane < SPG - 64) ? hist[64 + lane] : 0;
        int sc1 = v1;
#pragma unroll
        for (int m = 1; m < 64; m <<= 1) {
            int t = __shfl_up(sc1, m, 64);
            if (lane >= m) sc1 += t;
        }
        if (lane < SPG - 64 + 1) offsL[64 + lane] = tot0 + sc1 - v1;  // includes offsL[SPG]
        if (lane == 0) offsL[SPG] = cnt;
    }
    __syncthreads();
    for (int q = threadIdx.x; q < SPG + 1; q += 512) curL[q] = offsL[q];
    __syncthreads();
    // scatter rows into LDS (throughput ops, not on a latency chain)
    for (int i = threadIdx.x; i < cnt; i += 512) {
        unsigned int pk = src[i];
        int lc = (int)(pk & 16383u) - sbase;
        int pos = atomicAdd(&curL[lc], 1);
        adjL[pos] = (int)(pk >> 14);
    }
    __syncthreads();

    // gather phase: wave per node, stride 8
    int wid = threadIdx.x >> 6, lane = threadIdx.x & 63;
    float w0 = W2[lane * 2], w1 = W2[lane * 2 + 1], bv = b1[lane];
    for (int nd = wid; nd < ncols; nd += 8) {
        int st = offsL[nd], en = offsL[nd + 1];
        float acc0 = 0.f, acc1 = 0.f, acc2 = 0.f, acc3 = 0.f;
        int p = st;
        for (; p + 4 <= en; p += 4) {
            int s0 = adjL[p], s1 = adjL[p + 1], s2 = adjL[p + 2], s3 = adjL[p + 3];
            acc0 += __half2float(h1s[(size_t)s0 * 64 + lane]);
            acc1 += __half2float(h1s[(size_t)s1 * 64 + lane]);
            acc2 += __half2float(h1s[(size_t)s2 * 64 + lane]);
            acc3 += __half2float(h1s[(size_t)s3 * 64 + lane]);
        }
        int rem = en - p;
        if (rem > 0) {
            int q0 = adjL[p];
            int q1 = (rem > 1) ? adjL[p + 1] : q0;
            int q2 = (rem > 2) ? adjL[p + 2] : q0;
            float v0 = __half2float(h1s[(size_t)q0 * 64 + lane]);
            float v1 = __half2float(h1s[(size_t)q1 * 64 + lane]);
            float v2 = __half2float(h1s[(size_t)q2 * 64 + lane]);
            acc0 += v0;
            if (rem > 1) acc1 += v1;
            if (rem > 2) acc2 += v2;
        }
        float acc = (acc0 + acc1) + (acc2 + acc3);
        int i = colbase + nd;
        float di = dinv[i];
        float self = __half2float(h1s[(size_t)i * 64 + lane]);
        float val = fmaxf(fmaf(di, acc + self, bv), 0.f);
        float t0 = val * w0, t1 = val * w1;
#pragma unroll
        for (int m = 1; m < 64; m <<= 1) {
            t0 += __shfl_xor(t0, m, 64);
            t1 += __shfl_xor(t1, m, 64);
        }
        if (lane == 0) {
            h2s[(size_t)i * 2]     = t0 * di;
            h2s[(size_t)i * 2 + 1] = t1 * di;
        }
    }
}

// ---- Layer-2 aggregation from sub-buckets. Lane-per-edge, 8B gathers from
// L2-resident h2s, 2 LDS float atomics per edge.
__global__ __launch_bounds__(256) void k_agg2f(const float* __restrict__ h2s,
                                               const float* __restrict__ dinv,
                                               const unsigned int* __restrict__ pairs2,
                                               const int* __restrict__ bcur2,
                                               const float* __restrict__ b2,
                                               float* __restrict__ out, int npg) {
    __shared__ float acc2[SPG * 2];
    int sbid = blockIdx.x;
    int b = sbid >> 7, s = sbid & (NSUB - 1);
    int cnt = bcur2[sbid * 16];
    int sbase = s * SPG;
    int colbase = b * npg + sbase;
    int ncols = min(SPG, npg - sbase);
    const unsigned int* src = pairs2 + (size_t)sbid * CAP2;
    for (int q = threadIdx.x; q < SPG * 2; q += 256) acc2[q] = 0.f;
    __syncthreads();
    for (int i = threadIdx.x; i < cnt; i += 256) {
        unsigned int pk = src[i];
        int sn = (int)(pk >> 14);
        int lc = (int)(pk & 16383u) - sbase;
        float2 v = *(const float2*)(h2s + (size_t)sn * 2);
        atomicAdd(&acc2[lc * 2], v.x);
        atomicAdd(&acc2[lc * 2 + 1], v.y);
    }
    __syncthreads();
    if (threadIdx.x < ncols) {
        int i = colbase + threadIdx.x;
        float di = dinv[i];
        float2 hv = *(const float2*)(h2s + (size_t)i * 2);
        out[(size_t)i * 2]     = fmaf(di, acc2[threadIdx.x * 2] + hv.x, b2[0]);
        out[(size_t)i * 2 + 1] = fmaf(di, acc2[threadIdx.x * 2 + 1] + hv.y, b2[1]);
    }
}

extern "C" void kernel_launch(void* const* d_in, const int* in_sizes, int n_in,
                              void* d_out, int out_size, void* d_ws, size_t ws_size,
                              hipStream_t stream) {
    const float* x  = (const float*)d_in[0];
    const int*   ei = (const int*)d_in[1];
    const float* W1 = (const float*)d_in[2];
    const float* b1 = (const float*)d_in[3];
    const float* W2 = (const float*)d_in[4];
    const float* b2 = (const float*)d_in[5];
    float* out = (float*)d_out;

    int N = in_sizes[0] / 128;   // 100000
    int E = in_sizes[1] / 2;     // 1600000
    const int* row = ei;
    const int* col = ei + E;

    char* ws = (char*)d_ws;
    size_t off = 0;
    auto alloc = [&](size_t bytes) -> char* {
        char* p = ws + off;
        off = WS_ALIGN(off + bytes);
        return p;
    };
    int*   bcur   = (int*)alloc(512 + (size_t)NSB * 64);   // bcur (8x16) + bcur2 (1024x16)
    int*   bcur2  = bcur + 128;
    float* dinv   = (float*)alloc((size_t)N * 4);
    unsigned int* pairs1 = (unsigned int*)alloc((size_t)NB1 * CAP1 * 4);   // 8.4MB
    unsigned int* pairs2 = (unsigned int*)alloc((size_t)NSB * CAP2 * 4);   // 12.6MB
    __half* h1s   = (__half*)alloc((size_t)N * 64 * 2);    // 12.8MB fp16
    float* h2s    = (float*)alloc((size_t)N * 2 * 4);

    int npg = (N + 7) / 8;                                  // 12500
    unsigned int magic = (unsigned int)(((1ULL << 44) + (unsigned long long)npg - 1)
                                        / (unsigned long long)npg);
    unsigned int magic2 = (unsigned int)(((1u << 20) + SPG - 1) / SPG);  // /98, exact for lc<12544

    hipMemsetAsync(bcur, 0, 512 + (size_t)NSB * 64, stream);
    hipLaunchKernelGGL(k_bucket, dim3((E + 2047) / 2048), dim3(256), 0, stream,
                       row, col, bcur, pairs1, E, magic, npg);
    hipLaunchKernelGGL(k_refine, dim3(512), dim3(256), 0, stream,
                       pairs1, bcur, bcur2, pairs2, magic2);
    hipLaunchKernelGGL(k_degdinv, dim3(NSB), dim3(256), 0, stream, pairs2, bcur2, dinv, npg);
    hipLaunchKernelGGL(k_gemm1, dim3((N + 31) / 32), dim3(256), 0, stream, x, W1, dinv, h1s, N);
    hipLaunchKernelGGL(k_agg1s, dim3(NSB), dim3(512), 0, stream,
                       h1s, dinv, pairs2, bcur2, b1, W2, h2s, npg);
    hipLaunchKernelGGL(k_agg2f, dim3(NSB), dim3(256), 0, stream,
                       h2s, dinv, pairs2, bcur2, b2, out, npg);
}